// Round 10
// baseline (2757.709 us; speedup 1.0000x reference)
//
#include <hip/hip_runtime.h>
#include <stdint.h>

#define HDIM  512
#define NCLS  1000

typedef _Float16 f16x8 __attribute__((ext_vector_type(8)));
typedef float    f32x4 __attribute__((ext_vector_type(4)));
typedef unsigned long long u64;

// ---------------- workspace (bytes) ----------------
// xcv hi/lo : [64][512][256] f16 = 16 MB each (pre-converted x)
// rh  hi    : [3][4][64][512] f16 = 1.5 MB (h ring, depth 4)
// bar       : 4 group counters, 256 B apart
#define XCVH_OFF 0UL
#define XCVL_OFF 16777216UL
#define RHH_OFF  33554432UL
#define RHL_OFF  35127296UL
#define BAR_OFF  36700160UL
#define WS_NEED  (BAR_OFF + 4096UL)

// LDS layouts:
//  hb_hi [batch 16][oct' 0..191][8 f16], row = 193 octs * 8 = 1544 f16 (3088 B)
//        oct' 0..63 = h0, 64..127 = h1, 128..191 = h2  (x lives in xbuf)
//  xbuf  [plane 2][batch 16][oct 0..31][8 f16], row = 264 f16
//        double-buffered: waves 6-7 prefetch x[n+1] during MFMA phase
#define H_ROW   1544
#define HB_F16  (16 * H_ROW)      // 24704 f16 = 49408 B
#define XROW    264
#define XPLANE  (16 * XROW)       // 4224 f16 = 8448 B per plane-buffer

__device__ __forceinline__ float sigf(float x) {
    return 1.f / (1.f + __expf(-x));
}
__device__ __forceinline__ float tanh_fast(float x) {
    x = fminf(fmaxf(x, -15.f), 15.f);
    const float e = __expf(2.f * x);
    return (e - 1.f) / (e + 1.f);
}
struct f16pair { _Float16 h, l; };
__device__ __forceinline__ f16pair cvt2(float x) {
    f16pair p;
    p.h = (_Float16)x;
    p.l = (_Float16)(x - (float)p.h);
    return p;
}

// =====================================================================
// Prologue: x (f32) -> hi/lo f16 planes, once per call.
// =====================================================================
__global__ __launch_bounds__(256) void xcvt(
        const float* __restrict__ x, _Float16* __restrict__ xh,
        _Float16* __restrict__ xl, int n)
{
    const int stride = gridDim.x * 256;
    for (int i = blockIdx.x * 256 + threadIdx.x; i < n; i += stride) {
        const f16pair p = cvt2(x[i]);
        xh[i] = p.h;
        xl[i] = p.l;
    }
}

// =====================================================================
// Persistent pipelined 3-layer LSTM.  grid = 256 WGs x 512 thr (8 waves),
// 1 WG/CU.  WG: g = bid&3 (16 batches), s = bid>>2 (8 units).
// R9-verbatim structure (known-stable, 2620 us steady, no outlier mode):
//   - h ring staged via LLC-direct relaxed-agent atomic u64 loads
//   - h ring is f16 HI only; A = W rows f16 hi in 128 regs; x-lo kept (L0)
//   - barrier: tid0 atomicAdd + tid0-only short-window poll, s_sleep(1)
// Only change vs R9: h-stores packed 4 units -> one u64 store (lane
// pu==0 gathers pu 1..3 via two shfl_downs).  Halves outstanding stores
// in the pre-barrier drain and ~halves 32B-granule write waste
// (WRITE_SIZE 397 -> ~250 MB expected; numerics identical).
// =====================================================================
__global__ __launch_bounds__(512, 1) void lstm_mega(
        const _Float16* __restrict__ xh, const _Float16* __restrict__ xl,
        const float* __restrict__ Wih0, const float* __restrict__ Whh0,
        const float* __restrict__ bih0, const float* __restrict__ bhh0,
        const float* __restrict__ Wih1, const float* __restrict__ Whh1,
        const float* __restrict__ bih1, const float* __restrict__ bhh1,
        const float* __restrict__ Wih2, const float* __restrict__ Whh2,
        const float* __restrict__ bih2, const float* __restrict__ bhh2,
        _Float16* __restrict__ rhh,      // [3][4][64][512] hi plane
        _Float16* __restrict__ rhl,      // (unused)
        uint32_t* __restrict__ bar)      // cnt[g] @ bar + g*64 dwords
{
    __shared__ _Float16 hb_hi[HB_F16];        // 49408 B
    __shared__ _Float16 xb_hi[2 * XPLANE];    // 16896 B
    __shared__ _Float16 xb_lo[2 * XPLANE];    // 16896 B
    __shared__ float gates_w[6 * 16 * 17];    // per-wave 16x17 transpose, 6528 B

    const int tid  = threadIdx.x;
    const int bid  = blockIdx.x;
    const int g    = bid & 3;             // batch group (16 batches)
    const int s    = bid >> 2;            // unit slice: units 8s..8s+7
    uint32_t* cnt  = bar + g * 64;        // group counters 256 B apart

    const int wv   = tid >> 6;            // 0..7
    const int lane = tid & 63;
    const int m16  = lane & 15;
    const int quad = lane >> 4;

    // ---- A-fragments (waves 0-5): rows = 4 gates x 4 units, HI plane only
    f16x8 a_hi[32];
    const int lw    = wv >> 1;            // frag layer
    const int gtile = wv & 1;             // unit quad {4gt..4gt+3}
    const int nkt   = (lw == 0) ? 24 : 32;
    const int segN  = (lw == 0) ? 8 : 16;
    if (wv < 6) {
        const int gate = m16 >> 2;
        const int u4   = m16 & 3;
        const int grow = gate * 512 + (s << 3) + (gtile << 2) + u4;
        const float* Wih = (lw == 0) ? Wih0 : ((lw == 1) ? Wih1 : Wih2);
        const float* Whh = (lw == 0) ? Whh0 : ((lw == 1) ? Whh1 : Whh2);
        const int Kin = (lw == 0) ? 256 : 512;
        const float* srcA = Wih + (size_t)grow * Kin;
        const float* srcB = Whh + (size_t)grow * 512;
        #pragma unroll
        for (int kt = 0; kt < 32; kt++) {
            if (kt < nkt) {
                const float* sp = (kt < segN) ? srcA + kt * 32 + (quad << 3)
                                              : srcB + (kt - segN) * 32 + (quad << 3);
                const float4 w0 = *(const float4*)sp;
                const float4 w1 = *(const float4*)(sp + 4);
                a_hi[kt][0] = (_Float16)w0.x;
                a_hi[kt][1] = (_Float16)w0.y;
                a_hi[kt][2] = (_Float16)w0.z;
                a_hi[kt][3] = (_Float16)w0.w;
                a_hi[kt][4] = (_Float16)w1.x;
                a_hi[kt][5] = (_Float16)w1.y;
                a_hi[kt][6] = (_Float16)w1.z;
                a_hi[kt][7] = (_Float16)w1.w;
            }
        }
    }
    // hb oct' base: L0 h-part starts at kt=8 -> oct' 0; L1 -> 0; L2 -> 64
    const int obase = (lw == 0) ? -32 : ((lw == 1) ? 0 : 64);

    // ---- pointwise mapping (within MFMA wave): lane = batch*4 + unit4
    const int pb = lane >> 2;             // batch in group
    const int pu = lane & 3;              // unit within quad
    float bias_v[4];
    if (wv < 6) {
        const float* bi = (lw == 0) ? bih0 : ((lw == 1) ? bih1 : bih2);
        const float* bh = (lw == 0) ? bhh0 : ((lw == 1) ? bhh1 : bhh2);
        const int u = (s << 3) + (gtile << 2) + pu;
        #pragma unroll
        for (int gate = 0; gate < 4; gate++)
            bias_v[gate] = bi[gate * 512 + u] + bh[gate * 512 + u];
    }
    float c_reg = 0.f;

    // ---- staging mapping: sb = batch, ol = chunk lane
    const int sb  = tid >> 5;             // 0..15
    const int ol  = tid & 31;             // 0..31
    const int b64 = (g << 4) + sb;

    // ---- preamble: stage x[0] into xbuf plane 0 (plain cached loads)
    {
        const size_t off = (((size_t)b64 * 512) << 8) + (ol << 3);
        const f16x8 vh = *(const f16x8*)(xh + off);
        const f16x8 vl = *(const f16x8*)(xl + off);
        const int d = sb * XROW + (ol << 3);
        *(f16x8*)&xb_hi[d] = vh;
        *(f16x8*)&xb_lo[d] = vl;
    }

    for (int n = 0; n < 514; n++) {
        // ====== stage h ring (hi only): LLC-direct relaxed atomic u64 loads ======
        #pragma unroll
        for (int i = 0; i < 6; i++) {     // h_l[n-1-l], 64 octs per layer
            const int l    = i >> 1;
            const int octw = ol + ((i & 1) << 5);
            const int ts   = n - 1 - l;
            u64 qh0 = 0, qh1 = 0;
            if (ts >= 0 && ts < 512) {
                const size_t off = ((((size_t)l << 2) + (ts & 3)) * 64 + b64) * 512
                                 + ((size_t)octw << 3);
                u64* ph = (u64*)(rhh + off);
                qh0 = __hip_atomic_load(ph,     __ATOMIC_RELAXED, __HIP_MEMORY_SCOPE_AGENT);
                qh1 = __hip_atomic_load(ph + 1, __ATOMIC_RELAXED, __HIP_MEMORY_SCOPE_AGENT);
            }
            const int d = sb * H_ROW + (((l << 6) + octw) << 3);
            ((u64*)&hb_hi[d])[0] = qh0;
            ((u64*)&hb_hi[d])[1] = qh1;
        }
        __syncthreads();                  // syncB: staged operands ready

        const int tl = n - lw;            // this wave's time step
        if (wv < 6) {
            if (tl >= 0 && tl < 512) {
                // ====== MFMA: hi chains (parity) + x-lo chain (L0 only) ======
                const _Float16* xbh = xb_hi + (n & 1) * XPLANE + m16 * XROW;
                const _Float16* xbl = xb_lo + (n & 1) * XPLANE + m16 * XROW;
                const _Float16* hbh = hb_hi + m16 * H_ROW;
                f32x4 ac0 = {0.f, 0.f, 0.f, 0.f};
                f32x4 ac1 = {0.f, 0.f, 0.f, 0.f};
                f32x4 ac2 = {0.f, 0.f, 0.f, 0.f};
                __builtin_amdgcn_s_setprio(1);
                #pragma unroll
                for (int kt = 0; kt < 32; kt++) {
                    if (kt < nkt) {
                        const int co = ((kt << 2) + quad) << 3;
                        const bool fromx = (lw == 0) && (kt < 8);
                        const _Float16* sh = fromx ? xbh + co : hbh + ((obase << 3) + co);
                        const f16x8 bh8 = *(const f16x8*)sh;
                        if (kt & 1)
                            ac1 = __builtin_amdgcn_mfma_f32_16x16x32_f16(a_hi[kt], bh8, ac1, 0, 0, 0);
                        else
                            ac0 = __builtin_amdgcn_mfma_f32_16x16x32_f16(a_hi[kt], bh8, ac0, 0, 0, 0);
                        if ((lw == 0) && (kt < 8)) {     // x-lo correction, L0 only
                            const f16x8 bl8 = *(const f16x8*)(xbl + co);
                            ac2 = __builtin_amdgcn_mfma_f32_16x16x32_f16(a_hi[kt], bl8, ac2, 0, 0, 0);
                        }
                    }
                }
                __builtin_amdgcn_s_setprio(0);
                const f32x4 acc = (ac0 + ac1) + ac2;

                // ====== wave-private transpose: (row=gate*4+u4, col=batch) ======
                float* gw = gates_w + wv * 272;
                #pragma unroll
                for (int j = 0; j < 4; j++)
                    gw[((quad << 2) + j) * 17 + m16] = acc[j];
                // (compiler inserts lgkmcnt between ds_write and ds_read)

                // ====== pointwise: 1 (unit,batch) per lane ======
                const float vi = gw[(0 * 4 + pu) * 17 + pb] + bias_v[0];
                const float vf = gw[(1 * 4 + pu) * 17 + pb] + bias_v[1];
                const float vg = gw[(2 * 4 + pu) * 17 + pb] + bias_v[2];
                const float vo = gw[(3 * 4 + pu) * 17 + pb] + bias_v[3];
                const float gi = sigf(vi);
                const float gf = sigf(vf);
                const float gg = tanh_fast(vg);
                const float go = sigf(vo);
                const float c  = fmaf(gf, c_reg, gi * gg);
                c_reg = c;
                const float h = go * tanh_fast(c);
                const _Float16 hf = (_Float16)h;

                // quad-pack (4 units) -> one u64 store per (batch, quad)
                union { _Float16 f; uint16_t u; } Uh;
                Uh.f = hf;
                uint32_t w = (uint32_t)Uh.u;
                const uint32_t n1 = (uint32_t)__shfl_down((int)w, 1, 64);
                w |= n1 << 16;                          // pu 0: (u0,u1); pu 2: (u2,u3)
                const uint32_t n2 = (uint32_t)__shfl_down((int)w, 2, 64);
                if (pu == 0) {
                    const int u = (s << 3) + (gtile << 2);
                    const size_t off = ((((size_t)lw << 2) + (tl & 3)) * 64 + (g << 4) + pb) * 512 + u;
                    const u64 q = (u64)w | ((u64)n2 << 32);
                    __hip_atomic_store((u64*)(rhh + off), q,
                                       __ATOMIC_RELAXED, __HIP_MEMORY_SCOPE_AGENT);
                }
            }
        } else {
            // ====== waves 6-7: prefetch x[n+1] into back plane ======
            const int nx = n + 1;
            if (nx < 512) {
                const int th  = tid & 127;
                const int sb2 = th >> 3;          // batch
                const int og  = th & 7;           // 32-f16 chunk
                const size_t off = (((size_t)((g << 4) + sb2) * 512 + nx) << 8) + (og << 5);
                const int d = (nx & 1) * XPLANE + sb2 * XROW + (og << 5);
                #pragma unroll
                for (int kk = 0; kk < 4; kk++) {
                    const f16x8 vh = *(const f16x8*)(xh + off + (kk << 3));
                    const f16x8 vl = *(const f16x8*)(xl + off + (kk << 3));
                    *(f16x8*)&xb_hi[d + (kk << 3)] = vh;
                    *(f16x8*)&xb_lo[d + (kk << 3)] = vl;
                }
            }
        }

        // ====== group barrier: monotonic counter, tid0-only poll ======
        if (n < 513) {
            __syncthreads();              // syncC: all waves' stores drained (vmcnt 0)
            if (tid == 0) {
                __hip_atomic_fetch_add(cnt, 1u, __ATOMIC_RELAXED, __HIP_MEMORY_SCOPE_AGENT);
                const uint32_t tgt = (uint32_t)(n + 1) << 6;
                while (__hip_atomic_load(cnt, __ATOMIC_RELAXED, __HIP_MEMORY_SCOPE_AGENT) < tgt)
                    __builtin_amdgcn_s_sleep(1);
            }
            __syncthreads();              // syncA: release WG into next step
        }
    }
}

// =====================================================================
// FC head: out[b][c] = h2[b][:] . W_fc[c][:] + b_fc[c]   (hi plane only)
// grid = (64 batches, 4 class-chunks) -> 256 WGs.
// =====================================================================
__global__ __launch_bounds__(256) void fc_head(
        const _Float16* __restrict__ rhh, const _Float16* __restrict__ rhl,
        const float* __restrict__ Wfc, const float* __restrict__ bfc,
        float* __restrict__ out)           // [64][1000]
{
    __shared__ float hs[HDIM];
    const int b     = blockIdx.x;
    const int cbase = blockIdx.y * 250;
    // h2[t=511]: layer 2, slot 511&3 = 3
    const size_t off = ((size_t)(2 * 4 + 3) * 64 + b) * 512;
    for (int i = threadIdx.x; i < HDIM; i += 256)
        hs[i] = (float)rhh[off + i];
    __syncthreads();
    const int wave = threadIdx.x >> 6, lane = threadIdx.x & 63;
    for (int c = cbase + wave; c < cbase + 250; c += 4) {
        const float* wr = Wfc + (size_t)c * HDIM;
        float s = 0.f;
        for (int k = lane; k < HDIM; k += 64) s = fmaf(hs[k], wr[k], s);
        #pragma unroll
        for (int off2 = 32; off2 > 0; off2 >>= 1) s += __shfl_down(s, off2, 64);
        if (lane == 0) out[b * NCLS + c] = s + bfc[c];
    }
}

// =====================================================================
extern "C" void kernel_launch(void* const* d_in, const int* in_sizes, int n_in,
                              void* d_out, int out_size, void* d_ws, size_t ws_size,
                              hipStream_t stream)
{
    (void)in_sizes; (void)n_in; (void)out_size;
    if (ws_size < WS_NEED) return;   // readable failure instead of OOB fault

    const float* x    = (const float*)d_in[0];
    const float* Wih0 = (const float*)d_in[1];
    const float* Whh0 = (const float*)d_in[2];
    const float* bih0 = (const float*)d_in[3];
    const float* bhh0 = (const float*)d_in[4];
    const float* Wih1 = (const float*)d_in[5];
    const float* Whh1 = (const float*)d_in[6];
    const float* bih1 = (const float*)d_in[7];
    const float* bhh1 = (const float*)d_in[8];
    const float* Wih2 = (const float*)d_in[9];
    const float* Whh2 = (const float*)d_in[10];
    const float* bih2 = (const float*)d_in[11];
    const float* bhh2 = (const float*)d_in[12];
    const float* Wfc  = (const float*)d_in[13];
    const float* bfc  = (const float*)d_in[14];
    float* out = (float*)d_out;

    char* ws = (char*)d_ws;
    _Float16* xh  = (_Float16*)(ws + XCVH_OFF);
    _Float16* xl  = (_Float16*)(ws + XCVL_OFF);
    _Float16* rhh = (_Float16*)(ws + RHH_OFF);
    _Float16* rhl = (_Float16*)(ws + RHL_OFF);
    uint32_t* bar = (uint32_t*)(ws + BAR_OFF);

    (void)hipMemsetAsync(bar, 0, 4096, stream);
    xcvt<<<dim3(2048), dim3(256), 0, stream>>>(x, xh, xl, 64 * 512 * 256);

    lstm_mega<<<dim3(256), dim3(512), 0, stream>>>(
        xh, xl, Wih0, Whh0, bih0, bhh0, Wih1, Whh1, bih1, bhh1,
        Wih2, Whh2, bih2, bhh2, rhh, rhl, bar);

    fc_head<<<dim3(64, 4), dim3(256), 0, stream>>>(rhh, rhl, Wfc, bfc, out);
}

// Round 11
// 2698.096 us; speedup vs baseline: 1.0221x; 1.0221x over previous
//
#include <hip/hip_runtime.h>
#include <stdint.h>

#define HDIM  512
#define NCLS  1000

typedef _Float16 f16x8 __attribute__((ext_vector_type(8)));
typedef float    f32x4 __attribute__((ext_vector_type(4)));
typedef unsigned long long u64;

// ---------------- workspace (bytes) ----------------
// xcv hi/lo : [64][512][256] f16 = 16 MB each (pre-converted x)
// rh  hi    : [3][4][64][512] f16 = 1.5 MB (h ring, depth 4)
// bar       : 4 group counters, 256 B apart
#define XCVH_OFF 0UL
#define XCVL_OFF 16777216UL
#define RHH_OFF  33554432UL
#define RHL_OFF  35127296UL
#define BAR_OFF  36700160UL
#define WS_NEED  (BAR_OFF + 4096UL)

// LDS layouts:
//  hb_hi [batch 16][oct' 0..191][8 f16], row = 193 octs * 8 = 1544 f16 (3088 B)
//        oct' 0..63 = h0, 64..127 = h1, 128..191 = h2  (x lives in xbuf)
//  xbuf  [plane 2][batch 16][oct 0..31][8 f16], row = 264 f16
//        double-buffered: waves 6-7 prefetch x[n+1] during MFMA phase
#define H_ROW   1544
#define HB_F16  (16 * H_ROW)      // 24704 f16 = 49408 B
#define XROW    264
#define XPLANE  (16 * XROW)       // 4224 f16 = 8448 B per plane-buffer

__device__ __forceinline__ float sigf(float x) {
    return 1.f / (1.f + __expf(-x));
}
__device__ __forceinline__ float tanh_fast(float x) {
    x = fminf(fmaxf(x, -15.f), 15.f);
    const float e = __expf(2.f * x);
    return (e - 1.f) / (e + 1.f);
}
struct f16pair { _Float16 h, l; };
__device__ __forceinline__ f16pair cvt2(float x) {
    f16pair p;
    p.h = (_Float16)x;
    p.l = (_Float16)(x - (float)p.h);
    return p;
}

// =====================================================================
// Prologue: x (f32) -> hi/lo f16 planes, once per call.
// =====================================================================
__global__ __launch_bounds__(256) void xcvt(
        const float* __restrict__ x, _Float16* __restrict__ xh,
        _Float16* __restrict__ xl, int n)
{
    const int stride = gridDim.x * 256;
    for (int i = blockIdx.x * 256 + threadIdx.x; i < n; i += stride) {
        const f16pair p = cvt2(x[i]);
        xh[i] = p.h;
        xl[i] = p.l;
    }
}

// =====================================================================
// Persistent pipelined 3-layer LSTM.  grid = 256 WGs x 512 thr (8 waves),
// 1 WG/CU.  WG: g = bid&3 (16 batches), s = bid>>2 (8 units).
// R9-verbatim (best verified: 2708 us total, lstm 2620 us, stable):
//   - h ring staged via LLC-direct relaxed-agent atomic u64 loads
//   - h ring is f16 HI only (h-lo correction proven numerically inert)
//   - A = W rows f16 hi in 128 regs (fits 256/wave unified budget;
//     hi+lo would spill/remat - R2 lesson)
//   - x-lo correction kept (L0, cached xbuf path)
//   - barrier: tid0 atomicAdd + tid0-only short-window poll, s_sleep(1)
//     (only poll shape never showing the 45 ms contention mode)
//   - h stores: u32 pair-pack (R10's u64 quad-pack regressed: store
//     path is hidden, extra shfls are not)
// =====================================================================
__global__ __launch_bounds__(512, 1) void lstm_mega(
        const _Float16* __restrict__ xh, const _Float16* __restrict__ xl,
        const float* __restrict__ Wih0, const float* __restrict__ Whh0,
        const float* __restrict__ bih0, const float* __restrict__ bhh0,
        const float* __restrict__ Wih1, const float* __restrict__ Whh1,
        const float* __restrict__ bih1, const float* __restrict__ bhh1,
        const float* __restrict__ Wih2, const float* __restrict__ Whh2,
        const float* __restrict__ bih2, const float* __restrict__ bhh2,
        _Float16* __restrict__ rhh,      // [3][4][64][512] hi plane
        _Float16* __restrict__ rhl,      // (unused)
        uint32_t* __restrict__ bar)      // cnt[g] @ bar + g*64 dwords
{
    __shared__ _Float16 hb_hi[HB_F16];        // 49408 B
    __shared__ _Float16 xb_hi[2 * XPLANE];    // 16896 B
    __shared__ _Float16 xb_lo[2 * XPLANE];    // 16896 B
    __shared__ float gates_w[6 * 16 * 17];    // per-wave 16x17 transpose, 6528 B

    const int tid  = threadIdx.x;
    const int bid  = blockIdx.x;
    const int g    = bid & 3;             // batch group (16 batches)
    const int s    = bid >> 2;            // unit slice: units 8s..8s+7
    uint32_t* cnt  = bar + g * 64;        // group counters 256 B apart

    const int wv   = tid >> 6;            // 0..7
    const int lane = tid & 63;
    const int m16  = lane & 15;
    const int quad = lane >> 4;

    // ---- A-fragments (waves 0-5): rows = 4 gates x 4 units, HI plane only
    f16x8 a_hi[32];
    const int lw    = wv >> 1;            // frag layer
    const int gtile = wv & 1;             // unit quad {4gt..4gt+3}
    const int nkt   = (lw == 0) ? 24 : 32;
    const int segN  = (lw == 0) ? 8 : 16;
    if (wv < 6) {
        const int gate = m16 >> 2;
        const int u4   = m16 & 3;
        const int grow = gate * 512 + (s << 3) + (gtile << 2) + u4;
        const float* Wih = (lw == 0) ? Wih0 : ((lw == 1) ? Wih1 : Wih2);
        const float* Whh = (lw == 0) ? Whh0 : ((lw == 1) ? Whh1 : Whh2);
        const int Kin = (lw == 0) ? 256 : 512;
        const float* srcA = Wih + (size_t)grow * Kin;
        const float* srcB = Whh + (size_t)grow * 512;
        #pragma unroll
        for (int kt = 0; kt < 32; kt++) {
            if (kt < nkt) {
                const float* sp = (kt < segN) ? srcA + kt * 32 + (quad << 3)
                                              : srcB + (kt - segN) * 32 + (quad << 3);
                const float4 w0 = *(const float4*)sp;
                const float4 w1 = *(const float4*)(sp + 4);
                a_hi[kt][0] = (_Float16)w0.x;
                a_hi[kt][1] = (_Float16)w0.y;
                a_hi[kt][2] = (_Float16)w0.z;
                a_hi[kt][3] = (_Float16)w0.w;
                a_hi[kt][4] = (_Float16)w1.x;
                a_hi[kt][5] = (_Float16)w1.y;
                a_hi[kt][6] = (_Float16)w1.z;
                a_hi[kt][7] = (_Float16)w1.w;
            }
        }
    }
    // hb oct' base: L0 h-part starts at kt=8 -> oct' 0; L1 -> 0; L2 -> 64
    const int obase = (lw == 0) ? -32 : ((lw == 1) ? 0 : 64);

    // ---- pointwise mapping (within MFMA wave): lane = batch*4 + unit4
    const int pb = lane >> 2;             // batch in group
    const int pu = lane & 3;              // unit within quad
    float bias_v[4];
    if (wv < 6) {
        const float* bi = (lw == 0) ? bih0 : ((lw == 1) ? bih1 : bih2);
        const float* bh = (lw == 0) ? bhh0 : ((lw == 1) ? bhh1 : bhh2);
        const int u = (s << 3) + (gtile << 2) + pu;
        #pragma unroll
        for (int gate = 0; gate < 4; gate++)
            bias_v[gate] = bi[gate * 512 + u] + bh[gate * 512 + u];
    }
    float c_reg = 0.f;

    // ---- staging mapping: sb = batch, ol = chunk lane
    const int sb  = tid >> 5;             // 0..15
    const int ol  = tid & 31;             // 0..31
    const int b64 = (g << 4) + sb;

    // ---- preamble: stage x[0] into xbuf plane 0 (plain cached loads)
    {
        const size_t off = (((size_t)b64 * 512) << 8) + (ol << 3);
        const f16x8 vh = *(const f16x8*)(xh + off);
        const f16x8 vl = *(const f16x8*)(xl + off);
        const int d = sb * XROW + (ol << 3);
        *(f16x8*)&xb_hi[d] = vh;
        *(f16x8*)&xb_lo[d] = vl;
    }

    for (int n = 0; n < 514; n++) {
        // ====== stage h ring (hi only): LLC-direct relaxed atomic u64 loads ======
        #pragma unroll
        for (int i = 0; i < 6; i++) {     // h_l[n-1-l], 64 octs per layer
            const int l    = i >> 1;
            const int octw = ol + ((i & 1) << 5);
            const int ts   = n - 1 - l;
            u64 qh0 = 0, qh1 = 0;
            if (ts >= 0 && ts < 512) {
                const size_t off = ((((size_t)l << 2) + (ts & 3)) * 64 + b64) * 512
                                 + ((size_t)octw << 3);
                u64* ph = (u64*)(rhh + off);
                qh0 = __hip_atomic_load(ph,     __ATOMIC_RELAXED, __HIP_MEMORY_SCOPE_AGENT);
                qh1 = __hip_atomic_load(ph + 1, __ATOMIC_RELAXED, __HIP_MEMORY_SCOPE_AGENT);
            }
            const int d = sb * H_ROW + (((l << 6) + octw) << 3);
            ((u64*)&hb_hi[d])[0] = qh0;
            ((u64*)&hb_hi[d])[1] = qh1;
        }
        __syncthreads();                  // syncB: staged operands ready

        const int tl = n - lw;            // this wave's time step
        if (wv < 6) {
            if (tl >= 0 && tl < 512) {
                // ====== MFMA: hi chains (parity) + x-lo chain (L0 only) ======
                const _Float16* xbh = xb_hi + (n & 1) * XPLANE + m16 * XROW;
                const _Float16* xbl = xb_lo + (n & 1) * XPLANE + m16 * XROW;
                const _Float16* hbh = hb_hi + m16 * H_ROW;
                f32x4 ac0 = {0.f, 0.f, 0.f, 0.f};
                f32x4 ac1 = {0.f, 0.f, 0.f, 0.f};
                f32x4 ac2 = {0.f, 0.f, 0.f, 0.f};
                __builtin_amdgcn_s_setprio(1);
                #pragma unroll
                for (int kt = 0; kt < 32; kt++) {
                    if (kt < nkt) {
                        const int co = ((kt << 2) + quad) << 3;
                        const bool fromx = (lw == 0) && (kt < 8);
                        const _Float16* sh = fromx ? xbh + co : hbh + ((obase << 3) + co);
                        const f16x8 bh8 = *(const f16x8*)sh;
                        if (kt & 1)
                            ac1 = __builtin_amdgcn_mfma_f32_16x16x32_f16(a_hi[kt], bh8, ac1, 0, 0, 0);
                        else
                            ac0 = __builtin_amdgcn_mfma_f32_16x16x32_f16(a_hi[kt], bh8, ac0, 0, 0, 0);
                        if ((lw == 0) && (kt < 8)) {     // x-lo correction, L0 only
                            const f16x8 bl8 = *(const f16x8*)(xbl + co);
                            ac2 = __builtin_amdgcn_mfma_f32_16x16x32_f16(a_hi[kt], bl8, ac2, 0, 0, 0);
                        }
                    }
                }
                __builtin_amdgcn_s_setprio(0);
                const f32x4 acc = (ac0 + ac1) + ac2;

                // ====== wave-private transpose: (row=gate*4+u4, col=batch) ======
                float* gw = gates_w + wv * 272;
                #pragma unroll
                for (int j = 0; j < 4; j++)
                    gw[((quad << 2) + j) * 17 + m16] = acc[j];
                // (compiler inserts lgkmcnt between ds_write and ds_read)

                // ====== pointwise: 1 (unit,batch) per lane ======
                const float vi = gw[(0 * 4 + pu) * 17 + pb] + bias_v[0];
                const float vf = gw[(1 * 4 + pu) * 17 + pb] + bias_v[1];
                const float vg = gw[(2 * 4 + pu) * 17 + pb] + bias_v[2];
                const float vo = gw[(3 * 4 + pu) * 17 + pb] + bias_v[3];
                const float gi = sigf(vi);
                const float gf = sigf(vf);
                const float gg = tanh_fast(vg);
                const float go = sigf(vo);
                const float c  = fmaf(gf, c_reg, gi * gg);
                c_reg = c;
                const float h = go * tanh_fast(c);
                const _Float16 hf = (_Float16)h;

                // pair-pack (even,odd unit) -> u32 stores, keep EA granularity
                union { _Float16 f; uint16_t u; } Uh;
                Uh.f = hf;
                const uint32_t nh = (uint32_t)__shfl_down((int)(uint32_t)Uh.u, 1, 64);
                if ((pu & 1) == 0) {
                    const int u = (s << 3) + (gtile << 2) + pu;
                    const size_t off = ((((size_t)lw << 2) + (tl & 3)) * 64 + (g << 4) + pb) * 512 + u;
                    __hip_atomic_store((uint32_t*)(rhh + off), (uint32_t)Uh.u | (nh << 16),
                                       __ATOMIC_RELAXED, __HIP_MEMORY_SCOPE_AGENT);
                }
            }
        } else {
            // ====== waves 6-7: prefetch x[n+1] into back plane ======
            const int nx = n + 1;
            if (nx < 512) {
                const int th  = tid & 127;
                const int sb2 = th >> 3;          // batch
                const int og  = th & 7;           // 32-f16 chunk
                const size_t off = (((size_t)((g << 4) + sb2) * 512 + nx) << 8) + (og << 5);
                const int d = (nx & 1) * XPLANE + sb2 * XROW + (og << 5);
                #pragma unroll
                for (int kk = 0; kk < 4; kk++) {
                    const f16x8 vh = *(const f16x8*)(xh + off + (kk << 3));
                    const f16x8 vl = *(const f16x8*)(xl + off + (kk << 3));
                    *(f16x8*)&xb_hi[d + (kk << 3)] = vh;
                    *(f16x8*)&xb_lo[d + (kk << 3)] = vl;
                }
            }
        }

        // ====== group barrier: monotonic counter, tid0-only poll ======
        if (n < 513) {
            __syncthreads();              // syncC: all waves' stores drained (vmcnt 0)
            if (tid == 0) {
                __hip_atomic_fetch_add(cnt, 1u, __ATOMIC_RELAXED, __HIP_MEMORY_SCOPE_AGENT);
                const uint32_t tgt = (uint32_t)(n + 1) << 6;
                while (__hip_atomic_load(cnt, __ATOMIC_RELAXED, __HIP_MEMORY_SCOPE_AGENT) < tgt)
                    __builtin_amdgcn_s_sleep(1);
            }
            __syncthreads();              // syncA: release WG into next step
        }
    }
}

// =====================================================================
// FC head: out[b][c] = h2[b][:] . W_fc[c][:] + b_fc[c]   (hi plane only)
// grid = (64 batches, 4 class-chunks) -> 256 WGs.
// =====================================================================
__global__ __launch_bounds__(256) void fc_head(
        const _Float16* __restrict__ rhh, const _Float16* __restrict__ rhl,
        const float* __restrict__ Wfc, const float* __restrict__ bfc,
        float* __restrict__ out)           // [64][1000]
{
    __shared__ float hs[HDIM];
    const int b     = blockIdx.x;
    const int cbase = blockIdx.y * 250;
    // h2[t=511]: layer 2, slot 511&3 = 3
    const size_t off = ((size_t)(2 * 4 + 3) * 64 + b) * 512;
    for (int i = threadIdx.x; i < HDIM; i += 256)
        hs[i] = (float)rhh[off + i];
    __syncthreads();
    const int wave = threadIdx.x >> 6, lane = threadIdx.x & 63;
    for (int c = cbase + wave; c < cbase + 250; c += 4) {
        const float* wr = Wfc + (size_t)c * HDIM;
        float s = 0.f;
        for (int k = lane; k < HDIM; k += 64) s = fmaf(hs[k], wr[k], s);
        #pragma unroll
        for (int off2 = 32; off2 > 0; off2 >>= 1) s += __shfl_down(s, off2, 64);
        if (lane == 0) out[b * NCLS + c] = s + bfc[c];
    }
}

// =====================================================================
extern "C" void kernel_launch(void* const* d_in, const int* in_sizes, int n_in,
                              void* d_out, int out_size, void* d_ws, size_t ws_size,
                              hipStream_t stream)
{
    (void)in_sizes; (void)n_in; (void)out_size;
    if (ws_size < WS_NEED) return;   // readable failure instead of OOB fault

    const float* x    = (const float*)d_in[0];
    const float* Wih0 = (const float*)d_in[1];
    const float* Whh0 = (const float*)d_in[2];
    const float* bih0 = (const float*)d_in[3];
    const float* bhh0 = (const float*)d_in[4];
    const float* Wih1 = (const float*)d_in[5];
    const float* Whh1 = (const float*)d_in[6];
    const float* bih1 = (const float*)d_in[7];
    const float* bhh1 = (const float*)d_in[8];
    const float* Wih2 = (const float*)d_in[9];
    const float* Whh2 = (const float*)d_in[10];
    const float* bih2 = (const float*)d_in[11];
    const float* bhh2 = (const float*)d_in[12];
    const float* Wfc  = (const float*)d_in[13];
    const float* bfc  = (const float*)d_in[14];
    float* out = (float*)d_out;

    char* ws = (char*)d_ws;
    _Float16* xh  = (_Float16*)(ws + XCVH_OFF);
    _Float16* xl  = (_Float16*)(ws + XCVL_OFF);
    _Float16* rhh = (_Float16*)(ws + RHH_OFF);
    _Float16* rhl = (_Float16*)(ws + RHL_OFF);
    uint32_t* bar = (uint32_t*)(ws + BAR_OFF);

    (void)hipMemsetAsync(bar, 0, 4096, stream);
    xcvt<<<dim3(2048), dim3(256), 0, stream>>>(x, xh, xl, 64 * 512 * 256);

    lstm_mega<<<dim3(256), dim3(512), 0, stream>>>(
        xh, xl, Wih0, Whh0, bih0, bhh0, Wih1, Whh1, bih1, bhh1,
        Wih2, Whh2, bih2, bhh2, rhh, rhl, bar);

    fc_head<<<dim3(64, 4), dim3(256), 0, stream>>>(rhh, rhl, Wfc, bfc, out);
}